// Round 13
// baseline (254.275 us; speedup 1.0000x reference)
//
#include <hip/hip_runtime.h>
#include <hip/hip_bf16.h>

#define BB 4
#define SS 1024
#define DD 1024
#define HH 16
#define DH 64
#define MM (BB*SS)   // 4096

typedef __attribute__((ext_vector_type(8))) short bf16x8;
typedef __attribute__((ext_vector_type(8))) unsigned short u16x8;
typedef __attribute__((ext_vector_type(4))) float f32x4;

__device__ __forceinline__ float b2f(unsigned short u) {
    union { unsigned int i; float f; } c; c.i = ((unsigned int)u) << 16; return c.f;
}
__device__ __forceinline__ unsigned short f2b(float f) {
    __hip_bfloat16 h = __float2bfloat16(f);
    return *reinterpret_cast<unsigned short*>(&h);
}
__device__ __forceinline__ unsigned int pack2(float a, float b) {
    unsigned int r;
    asm("v_cvt_pk_bf16_f32 %0, %1, %2" : "=v"(r) : "v"(a), "v"(b));
    return r;
}
__device__ __forceinline__ void gload16(const unsigned short* g, unsigned short* l) {
    __builtin_amdgcn_global_load_lds(
        (const __attribute__((address_space(1))) void*)g,
        (__attribute__((address_space(3))) void*)l,
        16, 0, 0);
}
#define MFMA16(a, b, c) __builtin_amdgcn_mfma_f32_16x16x32_bf16(a, b, c, 0, 0, 0)

// ---------------------------------------------------------------------------
// prep_xw: fused prep_x (blocks 0..4095) + prep_w (blocks 4096..7167).
// ---------------------------------------------------------------------------
__global__ __launch_bounds__(256) void prep_xw_kernel(
    const float* __restrict__ x, const float* __restrict__ vx,
    const float* __restrict__ W0, const float* __restrict__ vW0,
    const float* __restrict__ W1, const float* __restrict__ vW1,
    const float* __restrict__ W2, const float* __restrict__ vW2,
    unsigned short* __restrict__ xb, unsigned short* __restrict__ vxb,
    unsigned short* __restrict__ xsb, unsigned short* __restrict__ wp)
{
    const int gx = blockIdx.x;
    if (gx < 4096) {
        const size_t i = ((size_t)gx * 256 + threadIdx.x) * 4;
        float4 a = *(const float4*)(x + i);
        float4 b = *(const float4*)(vx + i);
        ushort4 oa = { f2b(a.x), f2b(a.y), f2b(a.z), f2b(a.w) };
        ushort4 ob = { f2b(b.x), f2b(b.y), f2b(b.z), f2b(b.w) };
        ushort4 os = { f2b(a.x*a.x), f2b(a.y*a.y), f2b(a.z*a.z), f2b(a.w*a.w) };
        *(ushort4*)(xb  + i) = oa;
        *(ushort4*)(vxb + i) = ob;
        *(ushort4*)(xsb + i) = os;
    } else {
        const int bxx = gx - 4096;
        const int z   = bxx >> 10;
        const int bx  = bxx & 1023;
        const float* W  = (z==0)? W0 : (z==1)? W1 : W2;
        const float* vW = (z==0)? vW0: (z==1)? vW1: vW2;
        const size_t NW = (size_t)DD*DD;
        unsigned short* wb = wp + (size_t)(3*z+0)*NW;
        unsigned short* wc = wp + (size_t)(3*z+1)*NW;
        unsigned short* wv = wp + (size_t)(3*z+2)*NW;
        const size_t i = ((size_t)bx * 256 + threadIdx.x) * 4;
        float4 a = *(const float4*)(W + i);
        float4 b = *(const float4*)(vW + i);
        ushort4 oa = { f2b(a.x), f2b(a.y), f2b(a.z), f2b(a.w) };
        ushort4 oc = { f2b(a.x*a.x + b.x), f2b(a.y*a.y + b.y),
                       f2b(a.z*a.z + b.z), f2b(a.w*a.w + b.w) };
        ushort4 ov = { f2b(b.x), f2b(b.y), f2b(b.z), f2b(b.w) };
        *(ushort4*)(wb + i) = oa;
        *(ushort4*)(wc + i) = oc;
        *(ushort4*)(wv + i) = ov;
    }
}

// ---------------------------------------------------------------------------
// Fused projection GEMM (one dispatch, z = 0..5) — R12 (T1 swizzle kept).
// ---------------------------------------------------------------------------
__global__ __launch_bounds__(256) void gemm_proj_kernel(
    const unsigned short* __restrict__ xb, const unsigned short* __restrict__ vxb,
    const unsigned short* __restrict__ xsb,
    const unsigned short* __restrict__ wp,
    unsigned short* __restrict__ qm, unsigned short* __restrict__ km,
    unsigned short* __restrict__ vm,
    unsigned short* __restrict__ qv, unsigned short* __restrict__ kv,
    unsigned short* __restrict__ vvv)
{
    __shared__ unsigned short sA[2][128*32];
    __shared__ unsigned short sB[2][128*32];

    const int z = blockIdx.z;
    const size_t NW = (size_t)DD*DD;
    const bool isVar = (z >= 3);
    const int p = isVar ? (z - 3) : z;
    const unsigned short* A0 = isVar ? vxb : xb;
    const unsigned short* A1 = isVar ? xsb : xb;
    const unsigned short* B0 = wp + (size_t)(3*p + (isVar ? 1 : 0)) * NW;
    const unsigned short* B1 = isVar ? (wp + (size_t)(3*p + 2) * NW) : B0;
    unsigned short* Out = (z==0)? qm : (z==1)? km : (z==2)? vm
                        : (z==3)? qv : (z==4)? kv : vvv;
    const int NT = isVar ? 64 : 32;

    const int orig = blockIdx.x + (blockIdx.y << 3);
    const int swz  = ((orig & 7) << 5) | (orig >> 3);
    const int bn = swz & 7;
    const int bm = swz >> 3;

    const int tid = threadIdx.x;
    const int w = tid >> 6;
    const int l = tid & 63;
    const int wr = w >> 1, wc = w & 1;

    const int r0 = tid >> 2;
    const int s0 = (((tid & 3) ^ ((r0 >> 1) & 3)) * 8);
    const size_t aoff0 = (size_t)(bm*128 + r0) * DD + s0;
    const size_t boff0 = (size_t)(bn*128 + r0) * DD + s0;
    const int ldsd0 = (w*64) * 8;
    const int ldsd1 = (256 + w*64) * 8;

#define STG(buf, t) do {                                                   \
        const unsigned short* As_ = ((t) < 32) ? A0 : A1;                  \
        const unsigned short* Bs_ = ((t) < 32) ? B0 : B1;                  \
        const int kc_ = ((t) & 31) * 32;                                   \
        gload16(As_ + aoff0 + kc_,                   &sA[buf][ldsd0]);     \
        gload16(As_ + aoff0 + (size_t)64*DD + kc_,   &sA[buf][ldsd1]);     \
        gload16(Bs_ + boff0 + kc_,                   &sB[buf][ldsd0]);     \
        gload16(Bs_ + boff0 + (size_t)64*DD + kc_,   &sB[buf][ldsd1]);     \
    } while (0)

    f32x4 acc[4][4];
    #pragma unroll
    for (int i = 0; i < 4; ++i)
        #pragma unroll
        for (int j = 0; j < 4; ++j)
            acc[i][j] = (f32x4){0.f,0.f,0.f,0.f};

    const int fr = l & 15;
    const int hi = l >> 4;

    STG(0, 0);
    __syncthreads();

    for (int t = 0; t < NT; ++t) {
        const int cb = t & 1;
        if (t + 1 < NT) STG(cb ^ 1, t + 1);

        bf16x8 bfr[4];
        #pragma unroll
        for (int j = 0; j < 4; ++j) {
            const int row = wc*64 + j*16 + fr;
            bfr[j] = *(const bf16x8*)&sB[cb][row*32 + ((hi ^ ((row >> 1) & 3)) * 8)];
        }
        #pragma unroll
        for (int i = 0; i < 4; ++i) {
            const int row = wr*64 + i*16 + fr;
            bf16x8 a0 = *(const bf16x8*)&sA[cb][row*32 + ((hi ^ ((row >> 1) & 3)) * 8)];
            #pragma unroll
            for (int j = 0; j < 4; ++j)
                acc[i][j] = MFMA16(a0, bfr[j], acc[i][j]);
        }
        __syncthreads();
    }
#undef STG

    const int orow = bm*128 + wr*64 + (hi << 2);
    const int ocol = bn*128 + wc*64 + fr;
    #pragma unroll
    for (int i = 0; i < 4; ++i)
        #pragma unroll
        for (int j = 0; j < 4; ++j)
            #pragma unroll
            for (int r = 0; r < 4; ++r)
                Out[(size_t)(orow + i*16 + r) * DD + ocol + j*16] = f2b(acc[i][j][r]);
}

// ---------------------------------------------------------------------------
// prep_vtkk: fused V-transpose (+w=vv+v^2) [blocks 0..1023] and
// kk = vk + k^2 elementwise [blocks 1024..3071].
// ---------------------------------------------------------------------------
__global__ __launch_bounds__(256) void prep_vtkk_kernel(
    const unsigned short* __restrict__ vm, const unsigned short* __restrict__ vvv,
    const unsigned short* __restrict__ kmp, const unsigned short* __restrict__ kvp,
    unsigned short* __restrict__ vt, unsigned short* __restrict__ wt,
    unsigned short* __restrict__ vvt, unsigned short* __restrict__ kkb)
{
    __shared__ unsigned short tv[64][68];
    __shared__ unsigned short tw[64][68];
    __shared__ unsigned short tvv[64][68];
    const int t = threadIdx.x;
    const int gx = blockIdx.x;

    if (gx >= 1024) {
        const size_t i = ((size_t)(gx - 1024) * 256 + t) * 8;
        u16x8 k8 = *(const u16x8*)(kmp + i);
        u16x8 v8 = *(const u16x8*)(kvp + i);
        u16x8 o8;
        #pragma unroll
        for (int e = 0; e < 8; ++e) {
            float kf = b2f(k8[e]);
            o8[e] = f2b(b2f(v8[e]) + kf*kf);
        }
        *(u16x8*)(kkb + i) = o8;
        return;
    }

    const int jt = gx & 15, h = (gx >> 4) & 15, b = gx >> 8;
    const size_t ibase = (size_t)b*SS*DD + (size_t)h*DH;
    {
        const int j = t & 63, cg = t >> 6;
        const size_t ga = ibase + (size_t)(jt*64 + j)*DD + cg*16;
        #pragma unroll
        for (int hh = 0; hh < 2; ++hh) {
            u16x8 v8  = *(const u16x8*)(vm  + ga + hh*8);
            u16x8 vv8 = *(const u16x8*)(vvv + ga + hh*8);
            u16x8 w8;
            #pragma unroll
            for (int e = 0; e < 8; ++e) {
                float vf = b2f(v8[e]);
                w8[e] = f2b(b2f(vv8[e]) + vf*vf);
            }
            *(u16x8*)&tv[j][cg*16 + hh*8]  = v8;
            *(u16x8*)&tvv[j][cg*16 + hh*8] = vv8;
            *(u16x8*)&tw[j][cg*16 + hh*8]  = w8;
        }
    }
    __syncthreads();
    {
        const int d  = t >> 2;
        const int pc = t & 3;
        const int lc = pc ^ ((d >> 1) & 3);
        #pragma unroll
        for (int st = 0; st < 2; ++st) {
            u16x8 o0, o1, o2;
            #pragma unroll
            for (int e = 0; e < 8; ++e) {
                const int jl = st*32 + (e >> 2)*16 + lc*4 + (e & 3);
                o0[e] = tv[jl][d];
                o1[e] = tw[jl][d];
                o2[e] = tvv[jl][d];
            }
            const size_t ob = (size_t)((b*HH + h)*DH + d)*SS + jt*64 + st*32 + pc*8;
            *(u16x8*)(vt  + ob) = o0;
            *(u16x8*)(wt  + ob) = o1;
            *(u16x8*)(vvt + ob) = o2;
        }
    }
}

// ---------------------------------------------------------------------------
// MFMA attention VMP + residual, v7 = R8 compute, new sync schedule:
// 3-buffer staging + COUNTED vmcnt(6) + raw s_barrier (T4).
// Per iter t: wait(own stage(t) landed; stage(t+1) stays in flight) ->
// barrier -> issue stage(t+2) -> compute(t). Prefetch DMA gets ~2 tiles of
// compute to land instead of 1, and the barrier never drains to vmcnt(0).
// Safety: each wave drains to <=6 outstanding (its stage(t+1)) before the
// barrier => all waves' stage(t) landed; buffer (t+2)%3 was last read in
// compute(t-1), which precedes this barrier in every wave's program order.
// ---------------------------------------------------------------------------
union PW { unsigned int u[4]; bf16x8 v; };

__global__ __launch_bounds__(256, 3) void attn_mfma_kernel(
    const unsigned short* __restrict__ kmg, const unsigned short* __restrict__ kvg,
    const unsigned short* __restrict__ kkg,
    const unsigned short* __restrict__ vtg, const unsigned short* __restrict__ wtg,
    const unsigned short* __restrict__ vvtg,
    const unsigned short* __restrict__ qmg, const unsigned short* __restrict__ qvg,
    const float* __restrict__ x, const float* __restrict__ vx,
    float* __restrict__ om, float* __restrict__ ov)
{
    __shared__ unsigned short Ks[3][3][32*64];
    __shared__ unsigned short Vs[3][3][64*32];

    const int tid = threadIdx.x;
    const int w = tid >> 6, l = tid & 63;
    const int lo = l & 15, hi = l >> 4;

    const int fb = blockIdx.x;
    const int g  = ((fb >> 7) << 3) | (fb & 7);   // 0..63 = b*16+h
    const int qt = (fb >> 3) & 15;
    const int h  = g & 15;
    const int b  = g >> 4;

    const size_t xbase = (size_t)b*SS*DD + (size_t)h*DH;
    const size_t vbase = (size_t)(b*HH + h)*DH*SS;

    bf16x8 qA[2], vqA[2], qsA[2];
    {
        const int qrow = qt*64 + w*16 + lo;
        #pragma unroll
        for (int ks = 0; ks < 2; ++ks) {
            const size_t ga = xbase + (size_t)qrow*DD + ks*32 + hi*8;
            qA[ks]  = *(const bf16x8*)(qmg + ga);
            vqA[ks] = *(const bf16x8*)(qvg + ga);
            #pragma unroll
            for (int e = 0; e < 8; ++e) {
                float f = b2f((unsigned short)qA[ks][e]);
                qsA[ks][e] = (short)f2b(f*f);
            }
        }
    }
    bf16x8 onesB;
    #pragma unroll
    for (int e = 0; e < 8; ++e) onesB[e] = (short)0x3F80;

    f32x4 T1[4], T2[4], T3[4], T4[4], T5[4];
    f32x4 zac = {0.f,0.f,0.f,0.f}, e2vac = {0.f,0.f,0.f,0.f};
    #pragma unroll
    for (int cb = 0; cb < 4; ++cb) {
        T1[cb] = (f32x4){0.f,0.f,0.f,0.f};
        T2[cb] = (f32x4){0.f,0.f,0.f,0.f};
        T3[cb] = (f32x4){0.f,0.f,0.f,0.f};
        T4[cb] = (f32x4){0.f,0.f,0.f,0.f};
        T5[cb] = (f32x4){0.f,0.f,0.f,0.f};
    }

    const size_t koff = (size_t)(l >> 3)*DD + (size_t)(((l & 7) ^ ((l >> 3) & 7)) * 8);
    const size_t voff = (size_t)(l >> 2)*SS + (size_t)((l & 3) * 8);

    const float KE = 0.03125f * 1.44269504f;   // 1/sqrt(D) * log2(e)

#define IK(bu, m, p, G) gload16(G + xbase + (j0 + (size_t)(p)*8)*DD + koff, &Ks[bu][m][(p)*512])
#define IV(bu, m, p, G) gload16(G + vbase + (size_t)((p)*16)*SS + j0 + voff, &Vs[bu][m][(p)*512])
#define STAGE(tt, bu) do {                                                     \
        const size_t j0 = (size_t)(tt) * 32;                                   \
        if (w == 0)      { IK(bu,0,0,kmg); IK(bu,0,1,kmg); IK(bu,0,2,kmg);     \
                           IK(bu,0,3,kmg); IK(bu,1,0,kvg); IK(bu,1,1,kvg); }   \
        else if (w == 1) { IK(bu,1,2,kvg); IK(bu,1,3,kvg); IK(bu,2,0,kkg);     \
                           IK(bu,2,1,kkg); IK(bu,2,2,kkg); IK(bu,2,3,kkg); }   \
        else if (w == 2) { IV(bu,0,0,vtg); IV(bu,0,1,vtg); IV(bu,0,2,vtg);     \
                           IV(bu,0,3,vtg); IV(bu,1,0,wtg); IV(bu,1,1,wtg); }   \
        else             { IV(bu,1,2,wtg); IV(bu,1,3,wtg); IV(bu,2,0,vvtg);    \
                           IV(bu,2,1,vvtg); IV(bu,2,2,vvtg); IV(bu,2,3,vvtg); }\
    } while (0)

#define COMPUTE(bu) do {                                                         \
        PW pe, pe2, pev, pe3;                                                    \
        _Pragma("unroll")                                                        \
        for (int jb = 0; jb < 2; ++jb) {                                         \
            f32x4 aa = {0.f,0.f,0.f,0.f}, vva = {0.f,0.f,0.f,0.f};               \
            const int jrow = jb*16 + lo;                                         \
            _Pragma("unroll")                                                    \
            for (int ks = 0; ks < 2; ++ks) {                                     \
                const int co = jrow*64 + (((ks*4 + hi) ^ (lo & 7)) * 8);         \
                bf16x8 kB  = *(const bf16x8*)&Ks[bu][0][co];                     \
                bf16x8 vkB = *(const bf16x8*)&Ks[bu][1][co];                     \
                bf16x8 kkB = *(const bf16x8*)&Ks[bu][2][co];                     \
                aa  = MFMA16(kB,  qA[ks],  aa);                                  \
                vva = MFMA16(kkB, vqA[ks], vva);                                 \
                vva = MFMA16(vkB, qsA[ks], vva);                                 \
            }                                                                    \
            _Pragma("unroll")                                                    \
            for (int rp = 0; rp < 2; ++rp) {                                     \
                float e0 = exp2f(aa[rp*2]   * KE);                               \
                float e1 = exp2f(aa[rp*2+1] * KE);                               \
                float va0 = vva[rp*2], va1 = vva[rp*2+1];                        \
                float s0 = e0*e0,  s1 = e1*e1;                                   \
                float v0 = s0*va0, v1 = s1*va1;                                  \
                float t0 = v0*e0,  t1 = v1*e1;                                   \
                pe.u [jb*2+rp] = pack2(e0, e1);                                  \
                pe2.u[jb*2+rp] = pack2(s0, s1);                                  \
                pev.u[jb*2+rp] = pack2(v0, v1);                                  \
                pe3.u[jb*2+rp] = pack2(t0, t1);                                  \
            }                                                                    \
        }                                                                        \
        __builtin_amdgcn_s_setprio(1);                                           \
        zac   = MFMA16(pe.v,  onesB, zac);                                       \
        e2vac = MFMA16(pev.v, onesB, e2vac);                                     \
        _Pragma("unroll")                                                        \
        for (int cb = 0; cb < 4; ++cb) {                                         \
            const int vo = (cb*16 + lo)*32 + ((hi ^ ((lo >> 1) & 3)) * 8);       \
            bf16x8 vB  = *(const bf16x8*)&Vs[bu][0][vo];                         \
            bf16x8 wB  = *(const bf16x8*)&Vs[bu][1][vo];                         \
            bf16x8 vvB = *(const bf16x8*)&Vs[bu][2][vo];                         \
            T1[cb] = MFMA16(pe.v,  vB,  T1[cb]);                                 \
            T2[cb] = MFMA16(pev.v, wB,  T2[cb]);                                 \
            T3[cb] = MFMA16(pe3.v, wB,  T3[cb]);                                 \
            T4[cb] = MFMA16(pe2.v, wB,  T4[cb]);                                 \
            T5[cb] = MFMA16(pe2.v, vvB, T5[cb]);                                 \
        }                                                                        \
        __builtin_amdgcn_s_setprio(0);                                           \
    } while (0)

#define WAITB(N) do {                                                            \
        asm volatile("s_waitcnt vmcnt(" #N ")" ::: "memory");                    \
        __builtin_amdgcn_s_barrier();                                            \
        asm volatile("" ::: "memory");                                           \
    } while (0)

    STAGE(0, 0);
    STAGE(1, 1);

    // t = 0..29, 3-unrolled for compile-time buffer indices
    for (int tb = 0; tb < 30; tb += 3) {
        WAITB(6);  STAGE(tb + 2, 2);  COMPUTE(0);
        WAITB(6);  STAGE(tb + 3, 0);  COMPUTE(1);
        WAITB(6);  STAGE(tb + 4, 1);  COMPUTE(2);
    }
    // t = 30 (buf 0): stage(31) still in flight -> vmcnt(6)
    WAITB(6);  COMPUTE(0);
    // t = 31 (buf 1): nothing behind it -> full drain
    WAITB(0);  COMPUTE(1);

    const float IRD2 = 0.0009765625f;
    #pragma unroll
    for (int r = 0; r < 4; ++r) {
        const float Z     = zac[r];
        const float invZ  = 1.f / Z;
        const float invZ2 = invZ * invZ;
        const float sv    = e2vac[r] * IRD2 * invZ2;
        const int row = qt*64 + w*16 + hi*4 + r;
        #pragma unroll
        for (int cb = 0; cb < 4; ++cb) {
            const size_t gi = xbase + (size_t)row*DD + cb*16 + lo;
            const float o  = T1[cb][r] * invZ;
            const float vo = (T2[cb][r]*IRD2 + sv*T4[cb][r] + T5[cb][r]) * invZ2
                           - 2.f * T3[cb][r] * IRD2 * invZ2 * invZ;
            om[gi] = x[gi] + o;
            ov[gi] = vx[gi] + vo;
        }
    }
#undef IK
#undef IV
#undef STAGE
#undef COMPUTE
#undef WAITB
}

extern "C" void kernel_launch(void* const* d_in, const int* in_sizes, int n_in,
                              void* d_out, int out_size, void* d_ws, size_t ws_size,
                              hipStream_t stream) {
    const float* x    = (const float*)d_in[0];
    const float* vx   = (const float*)d_in[1];
    const float* Wq   = (const float*)d_in[2];
    const float* vWq  = (const float*)d_in[3];
    const float* Wk   = (const float*)d_in[4];
    const float* vWk  = (const float*)d_in[5];
    const float* Wv   = (const float*)d_in[6];
    const float* vWv  = (const float*)d_in[7];

    const size_t NE = (size_t)MM * DD;

    unsigned short* u = (unsigned short*)d_ws;
    unsigned short* qm   = u + 0*NE;
    unsigned short* qv   = u + 1*NE;
    unsigned short* km   = u + 2*NE;
    unsigned short* kv   = u + 3*NE;
    unsigned short* vm   = u + 4*NE;
    unsigned short* vvv  = u + 5*NE;
    unsigned short* xbb  = u + 6*NE;   // after gemms: reused as vt
    unsigned short* vxbb = u + 7*NE;   // after gemms: reused as wt
    unsigned short* xsbb = u + 8*NE;   // after gemms: reused as vvt
    unsigned short* wp   = u + 9*NE;   // 9 weight mats; after gemms: reused as kk

    float* om = (float*)d_out;
    float* ov = om + NE;

    prep_xw_kernel<<<7168, 256, 0, stream>>>(x, vx, Wq, vWq, Wk, vWk, Wv, vWv,
                                             xbb, vxbb, xsbb, wp);

    dim3 gg(8, 32, 6);
    gemm_proj_kernel<<<gg, 256, 0, stream>>>(xbb, vxbb, xsbb, wp,
                                             qm, km, vm, qv, kv, vvv);

    unsigned short* vt  = xbb;
    unsigned short* wt  = vxbb;
    unsigned short* vvt = xsbb;
    unsigned short* kkb = wp;
    prep_vtkk_kernel<<<3072, 256, 0, stream>>>(vm, vvv, km, kv,
                                               vt, wt, vvt, kkb);

    attn_mfma_kernel<<<1024, 256, 0, stream>>>(km, kv, kkb, vt, wt, vvt,
                                               qm, qv, x, vx, om, ov);
}

// Round 14
// 214.562 us; speedup vs baseline: 1.1851x; 1.1851x over previous
//
#include <hip/hip_runtime.h>
#include <hip/hip_bf16.h>

#define BB 4
#define SS 1024
#define DD 1024
#define HH 16
#define DH 64
#define MM (BB*SS)   // 4096

typedef __attribute__((ext_vector_type(8))) short bf16x8;
typedef __attribute__((ext_vector_type(8))) unsigned short u16x8;
typedef __attribute__((ext_vector_type(4))) float f32x4;

__device__ __forceinline__ float b2f(unsigned short u) {
    union { unsigned int i; float f; } c; c.i = ((unsigned int)u) << 16; return c.f;
}
__device__ __forceinline__ float bitsf(unsigned int u) {
    union { unsigned int i; float f; } c; c.i = u; return c.f;
}
__device__ __forceinline__ unsigned short f2b(float f) {
    __hip_bfloat16 h = __float2bfloat16(f);
    return *reinterpret_cast<unsigned short*>(&h);
}
__device__ __forceinline__ unsigned int pack2(float a, float b) {
    unsigned int r;
    asm("v_cvt_pk_bf16_f32 %0, %1, %2" : "=v"(r) : "v"(a), "v"(b));
    return r;
}
__device__ __forceinline__ void gload16(const unsigned short* g, unsigned short* l) {
    __builtin_amdgcn_global_load_lds(
        (const __attribute__((address_space(1))) void*)g,
        (__attribute__((address_space(3))) void*)l,
        16, 0, 0);
}
#define MFMA16(a, b, c) __builtin_amdgcn_mfma_f32_16x16x32_bf16(a, b, c, 0, 0, 0)

// ---------------------------------------------------------------------------
// prep_xw: fused prep_x (blocks 0..4095) + prep_w (blocks 4096..7167).
// ---------------------------------------------------------------------------
__global__ __launch_bounds__(256) void prep_xw_kernel(
    const float* __restrict__ x, const float* __restrict__ vx,
    const float* __restrict__ W0, const float* __restrict__ vW0,
    const float* __restrict__ W1, const float* __restrict__ vW1,
    const float* __restrict__ W2, const float* __restrict__ vW2,
    unsigned short* __restrict__ xb, unsigned short* __restrict__ vxb,
    unsigned short* __restrict__ xsb, unsigned short* __restrict__ wp)
{
    const int gx = blockIdx.x;
    if (gx < 4096) {
        const size_t i = ((size_t)gx * 256 + threadIdx.x) * 4;
        float4 a = *(const float4*)(x + i);
        float4 b = *(const float4*)(vx + i);
        ushort4 oa = { f2b(a.x), f2b(a.y), f2b(a.z), f2b(a.w) };
        ushort4 ob = { f2b(b.x), f2b(b.y), f2b(b.z), f2b(b.w) };
        ushort4 os = { f2b(a.x*a.x), f2b(a.y*a.y), f2b(a.z*a.z), f2b(a.w*a.w) };
        *(ushort4*)(xb  + i) = oa;
        *(ushort4*)(vxb + i) = ob;
        *(ushort4*)(xsb + i) = os;
    } else {
        const int bxx = gx - 4096;
        const int z   = bxx >> 10;
        const int bx  = bxx & 1023;
        const float* W  = (z==0)? W0 : (z==1)? W1 : W2;
        const float* vW = (z==0)? vW0: (z==1)? vW1: vW2;
        const size_t NW = (size_t)DD*DD;
        unsigned short* wb = wp + (size_t)(3*z+0)*NW;
        unsigned short* wc = wp + (size_t)(3*z+1)*NW;
        unsigned short* wv = wp + (size_t)(3*z+2)*NW;
        const size_t i = ((size_t)bx * 256 + threadIdx.x) * 4;
        float4 a = *(const float4*)(W + i);
        float4 b = *(const float4*)(vW + i);
        ushort4 oa = { f2b(a.x), f2b(a.y), f2b(a.z), f2b(a.w) };
        ushort4 oc = { f2b(a.x*a.x + b.x), f2b(a.y*a.y + b.y),
                       f2b(a.z*a.z + b.z), f2b(a.w*a.w + b.w) };
        ushort4 ov = { f2b(b.x), f2b(b.y), f2b(b.z), f2b(b.w) };
        *(ushort4*)(wb + i) = oa;
        *(ushort4*)(wc + i) = oc;
        *(ushort4*)(wv + i) = ov;
    }
}

// ---------------------------------------------------------------------------
// Fused projection GEMM (one dispatch, z = 0..5) — unchanged from R12.
// ---------------------------------------------------------------------------
__global__ __launch_bounds__(256) void gemm_proj_kernel(
    const unsigned short* __restrict__ xb, const unsigned short* __restrict__ vxb,
    const unsigned short* __restrict__ xsb,
    const unsigned short* __restrict__ wp,
    unsigned short* __restrict__ qm, unsigned short* __restrict__ km,
    unsigned short* __restrict__ vm,
    unsigned short* __restrict__ qv, unsigned short* __restrict__ kv,
    unsigned short* __restrict__ vvv)
{
    __shared__ unsigned short sA[2][128*32];
    __shared__ unsigned short sB[2][128*32];

    const int z = blockIdx.z;
    const size_t NW = (size_t)DD*DD;
    const bool isVar = (z >= 3);
    const int p = isVar ? (z - 3) : z;
    const unsigned short* A0 = isVar ? vxb : xb;
    const unsigned short* A1 = isVar ? xsb : xb;
    const unsigned short* B0 = wp + (size_t)(3*p + (isVar ? 1 : 0)) * NW;
    const unsigned short* B1 = isVar ? (wp + (size_t)(3*p + 2) * NW) : B0;
    unsigned short* Out = (z==0)? qm : (z==1)? km : (z==2)? vm
                        : (z==3)? qv : (z==4)? kv : vvv;
    const int NT = isVar ? 64 : 32;

    const int orig = blockIdx.x + (blockIdx.y << 3);
    const int swz  = ((orig & 7) << 5) | (orig >> 3);
    const int bn = swz & 7;
    const int bm = swz >> 3;

    const int tid = threadIdx.x;
    const int w = tid >> 6;
    const int l = tid & 63;
    const int wr = w >> 1, wc = w & 1;

    const int r0 = tid >> 2;
    const int s0 = (((tid & 3) ^ ((r0 >> 1) & 3)) * 8);
    const size_t aoff0 = (size_t)(bm*128 + r0) * DD + s0;
    const size_t boff0 = (size_t)(bn*128 + r0) * DD + s0;
    const int ldsd0 = (w*64) * 8;
    const int ldsd1 = (256 + w*64) * 8;

#define STG(buf, t) do {                                                   \
        const unsigned short* As_ = ((t) < 32) ? A0 : A1;                  \
        const unsigned short* Bs_ = ((t) < 32) ? B0 : B1;                  \
        const int kc_ = ((t) & 31) * 32;                                   \
        gload16(As_ + aoff0 + kc_,                   &sA[buf][ldsd0]);     \
        gload16(As_ + aoff0 + (size_t)64*DD + kc_,   &sA[buf][ldsd1]);     \
        gload16(Bs_ + boff0 + kc_,                   &sB[buf][ldsd0]);     \
        gload16(Bs_ + boff0 + (size_t)64*DD + kc_,   &sB[buf][ldsd1]);     \
    } while (0)

    f32x4 acc[4][4];
    #pragma unroll
    for (int i = 0; i < 4; ++i)
        #pragma unroll
        for (int j = 0; j < 4; ++j)
            acc[i][j] = (f32x4){0.f,0.f,0.f,0.f};

    const int fr = l & 15;
    const int hi = l >> 4;

    STG(0, 0);
    __syncthreads();

    for (int t = 0; t < NT; ++t) {
        const int cb = t & 1;
        if (t + 1 < NT) STG(cb ^ 1, t + 1);

        bf16x8 bfr[4];
        #pragma unroll
        for (int j = 0; j < 4; ++j) {
            const int row = wc*64 + j*16 + fr;
            bfr[j] = *(const bf16x8*)&sB[cb][row*32 + ((hi ^ ((row >> 1) & 3)) * 8)];
        }
        #pragma unroll
        for (int i = 0; i < 4; ++i) {
            const int row = wr*64 + i*16 + fr;
            bf16x8 a0 = *(const bf16x8*)&sA[cb][row*32 + ((hi ^ ((row >> 1) & 3)) * 8)];
            #pragma unroll
            for (int j = 0; j < 4; ++j)
                acc[i][j] = MFMA16(a0, bfr[j], acc[i][j]);
        }
        __syncthreads();
    }
#undef STG

    const int orow = bm*128 + wr*64 + (hi << 2);
    const int ocol = bn*128 + wc*64 + fr;
    #pragma unroll
    for (int i = 0; i < 4; ++i)
        #pragma unroll
        for (int j = 0; j < 4; ++j)
            #pragma unroll
            for (int r = 0; r < 4; ++r)
                Out[(size_t)(orow + i*16 + r) * DD + ocol + j*16] = f2b(acc[i][j][r]);
}

// ---------------------------------------------------------------------------
// prep_vtkk: V-transpose (vt, vvt only — wt now computed in-attn) and kk.
// ---------------------------------------------------------------------------
__global__ __launch_bounds__(256) void prep_vtkk_kernel(
    const unsigned short* __restrict__ vm, const unsigned short* __restrict__ vvv,
    const unsigned short* __restrict__ kmp, const unsigned short* __restrict__ kvp,
    unsigned short* __restrict__ vt, unsigned short* __restrict__ vvt,
    unsigned short* __restrict__ kkb)
{
    __shared__ unsigned short tv[64][68];
    __shared__ unsigned short tvv[64][68];
    const int t = threadIdx.x;
    const int gx = blockIdx.x;

    if (gx >= 1024) {
        const size_t i = ((size_t)(gx - 1024) * 256 + t) * 8;
        u16x8 k8 = *(const u16x8*)(kmp + i);
        u16x8 v8 = *(const u16x8*)(kvp + i);
        u16x8 o8;
        #pragma unroll
        for (int e = 0; e < 8; ++e) {
            float kf = b2f(k8[e]);
            o8[e] = f2b(b2f(v8[e]) + kf*kf);
        }
        *(u16x8*)(kkb + i) = o8;
        return;
    }

    const int jt = gx & 15, h = (gx >> 4) & 15, b = gx >> 8;
    const size_t ibase = (size_t)b*SS*DD + (size_t)h*DH;
    {
        const int j = t & 63, cg = t >> 6;
        const size_t ga = ibase + (size_t)(jt*64 + j)*DD + cg*16;
        #pragma unroll
        for (int hh = 0; hh < 2; ++hh) {
            u16x8 v8  = *(const u16x8*)(vm  + ga + hh*8);
            u16x8 vv8 = *(const u16x8*)(vvv + ga + hh*8);
            *(u16x8*)&tv[j][cg*16 + hh*8]  = v8;
            *(u16x8*)&tvv[j][cg*16 + hh*8] = vv8;
        }
    }
    __syncthreads();
    {
        const int d  = t >> 2;
        const int pc = t & 3;
        const int lc = pc ^ ((d >> 1) & 3);
        #pragma unroll
        for (int st = 0; st < 2; ++st) {
            u16x8 o0, o2;
            #pragma unroll
            for (int e = 0; e < 8; ++e) {
                const int jl = st*32 + (e >> 2)*16 + lc*4 + (e & 3);
                o0[e] = tv[jl][d];
                o2[e] = tvv[jl][d];
            }
            const size_t ob = (size_t)((b*HH + h)*DH + d)*SS + jt*64 + st*32 + pc*8;
            *(u16x8*)(vt  + ob) = o0;
            *(u16x8*)(vvt + ob) = o2;
        }
    }
}

// ---------------------------------------------------------------------------
// MFMA attention VMP + residual, v8 = R8/R12 structure (2-buffer, one
// __syncthreads per tile, 4 waves, QBLK=64, grid 1024) with the wt V-stream
// ELIMINATED: wB = vvB + vB^2 computed in-register from the two streams
// already read (7 VALU per u32, RNE-identical to the old prep). LDS reads
// 24 -> 20 b128/tile; LDS 48KB -> 40KB.
// ---------------------------------------------------------------------------
union PW { unsigned int u[4]; bf16x8 v; };

__global__ __launch_bounds__(256, 3) void attn_mfma_kernel(
    const unsigned short* __restrict__ kmg, const unsigned short* __restrict__ kvg,
    const unsigned short* __restrict__ kkg,
    const unsigned short* __restrict__ vtg, const unsigned short* __restrict__ vvtg,
    const unsigned short* __restrict__ qmg, const unsigned short* __restrict__ qvg,
    const float* __restrict__ x, const float* __restrict__ vx,
    float* __restrict__ om, float* __restrict__ ov)
{
    __shared__ unsigned short Ks[2][3][32*64];
    __shared__ unsigned short Vs[2][2][64*32];

    const int tid = threadIdx.x;
    const int w = tid >> 6, l = tid & 63;
    const int lo = l & 15, hi = l >> 4;

    const int fb = blockIdx.x;
    const int g  = ((fb >> 7) << 3) | (fb & 7);   // 0..63 = b*16+h
    const int qt = (fb >> 3) & 15;
    const int h  = g & 15;
    const int b  = g >> 4;

    const size_t xbase = (size_t)b*SS*DD + (size_t)h*DH;
    const size_t vbase = (size_t)(b*HH + h)*DH*SS;

    bf16x8 qA[2], vqA[2], qsA[2];
    {
        const int qrow = qt*64 + w*16 + lo;
        #pragma unroll
        for (int ks = 0; ks < 2; ++ks) {
            const size_t ga = xbase + (size_t)qrow*DD + ks*32 + hi*8;
            qA[ks]  = *(const bf16x8*)(qmg + ga);
            vqA[ks] = *(const bf16x8*)(qvg + ga);
            #pragma unroll
            for (int e = 0; e < 8; ++e) {
                float f = b2f((unsigned short)qA[ks][e]);
                qsA[ks][e] = (short)f2b(f*f);
            }
        }
    }
    bf16x8 onesB;
    #pragma unroll
    for (int e = 0; e < 8; ++e) onesB[e] = (short)0x3F80;

    f32x4 T1[4], T2[4], T3[4], T4[4], T5[4];
    f32x4 zac = {0.f,0.f,0.f,0.f}, e2vac = {0.f,0.f,0.f,0.f};
    #pragma unroll
    for (int cb = 0; cb < 4; ++cb) {
        T1[cb] = (f32x4){0.f,0.f,0.f,0.f};
        T2[cb] = (f32x4){0.f,0.f,0.f,0.f};
        T3[cb] = (f32x4){0.f,0.f,0.f,0.f};
        T4[cb] = (f32x4){0.f,0.f,0.f,0.f};
        T5[cb] = (f32x4){0.f,0.f,0.f,0.f};
    }

    const size_t koff = (size_t)(l >> 3)*DD + (size_t)(((l & 7) ^ ((l >> 3) & 7)) * 8);
    const size_t voff = (size_t)(l >> 2)*SS + (size_t)((l & 3) * 8);

    const float KE = 0.03125f * 1.44269504f;   // 1/sqrt(D) * log2(e)

#define IK(bu, m, p, G) gload16(G + xbase + (j0 + (size_t)(p)*8)*DD + koff, &Ks[bu][m][(p)*512])
#define IV(bu, m, p, G) gload16(G + vbase + (size_t)((p)*16)*SS + j0 + voff, &Vs[bu][m][(p)*512])
#define STAGE(tt, bu) do {                                                     \
        const size_t j0 = (size_t)(tt) * 32;                                   \
        if (w == 0)      { IK(bu,0,0,kmg); IK(bu,0,1,kmg); IK(bu,0,2,kmg);     \
                           IK(bu,0,3,kmg); IK(bu,1,0,kvg); }                   \
        else if (w == 1) { IK(bu,1,1,kvg); IK(bu,1,2,kvg); IK(bu,1,3,kvg);     \
                           IK(bu,2,0,kkg); IK(bu,2,1,kkg); }                   \
        else if (w == 2) { IK(bu,2,2,kkg); IK(bu,2,3,kkg); IV(bu,0,0,vtg);     \
                           IV(bu,0,1,vtg); IV(bu,0,2,vtg); }                   \
        else             { IV(bu,0,3,vtg); IV(bu,1,0,vvtg); IV(bu,1,1,vvtg);   \
                           IV(bu,1,2,vvtg); IV(bu,1,3,vvtg); }                 \
    } while (0)

    STAGE(0, 0);
    __syncthreads();

    int cur = 0;
    for (int t = 0; t < SS/32; ++t) {
        if (t + 1 < SS/32) STAGE(t + 1, cur ^ 1);

        PW pe, pe2, pev, pe3;
        #pragma unroll
        for (int jb = 0; jb < 2; ++jb) {
            f32x4 aa = {0.f,0.f,0.f,0.f}, vva = {0.f,0.f,0.f,0.f};
            const int jrow = jb*16 + lo;
            #pragma unroll
            for (int ks = 0; ks < 2; ++ks) {
                const int co = jrow*64 + (((ks*4 + hi) ^ (lo & 7)) * 8);
                bf16x8 kB  = *(const bf16x8*)&Ks[cur][0][co];
                bf16x8 vkB = *(const bf16x8*)&Ks[cur][1][co];
                bf16x8 kkB = *(const bf16x8*)&Ks[cur][2][co];
                aa  = MFMA16(kB,  qA[ks],  aa);
                vva = MFMA16(kkB, vqA[ks], vva);
                vva = MFMA16(vkB, qsA[ks], vva);
            }
            #pragma unroll
            for (int rp = 0; rp < 2; ++rp) {
                float e0 = exp2f(aa[rp*2]   * KE);
                float e1 = exp2f(aa[rp*2+1] * KE);
                float va0 = vva[rp*2], va1 = vva[rp*2+1];   // unscaled (x1024)
                float s0 = e0*e0,  s1 = e1*e1;
                float v0 = s0*va0, v1 = s1*va1;
                float t0 = v0*e0,  t1 = v1*e1;
                pe.u [jb*2+rp] = pack2(e0, e1);
                pe2.u[jb*2+rp] = pack2(s0, s1);
                pev.u[jb*2+rp] = pack2(v0, v1);
                pe3.u[jb*2+rp] = pack2(t0, t1);
            }
        }

        __builtin_amdgcn_s_setprio(1);
        zac   = MFMA16(pe.v,  onesB, zac);
        e2vac = MFMA16(pev.v, onesB, e2vac);
        #pragma unroll
        for (int cb = 0; cb < 4; ++cb) {
            const int vo = (cb*16 + lo)*32 + ((hi ^ ((lo >> 1) & 3)) * 8);
            PW pv_, pvv_, wW;
            pv_.v  = *(const bf16x8*)&Vs[cur][0][vo];
            pvv_.v = *(const bf16x8*)&Vs[cur][1][vo];
            #pragma unroll
            for (int u = 0; u < 4; ++u) {
                const float v_lo  = bitsf(pv_.u[u] << 16);
                const float v_hi  = bitsf(pv_.u[u] & 0xffff0000u);
                const float vv_lo = bitsf(pvv_.u[u] << 16);
                const float vv_hi = bitsf(pvv_.u[u] & 0xffff0000u);
                wW.u[u] = pack2(fmaf(v_lo, v_lo, vv_lo), fmaf(v_hi, v_hi, vv_hi));
            }
            T1[cb] = MFMA16(pe.v,  pv_.v,  T1[cb]);
            T2[cb] = MFMA16(pev.v, wW.v,   T2[cb]);
            T3[cb] = MFMA16(pe3.v, wW.v,   T3[cb]);
            T4[cb] = MFMA16(pe2.v, wW.v,   T4[cb]);
            T5[cb] = MFMA16(pe2.v, pvv_.v, T5[cb]);
        }
        __builtin_amdgcn_s_setprio(0);

        __syncthreads();
        cur ^= 1;
    }

    const float IRD2 = 0.0009765625f;
    #pragma unroll
    for (int r = 0; r < 4; ++r) {
        const float Z     = zac[r];
        const float invZ  = 1.f / Z;
        const float invZ2 = invZ * invZ;
        const float sv    = e2vac[r] * IRD2 * invZ2;
        const int row = qt*64 + w*16 + hi*4 + r;
        #pragma unroll
        for (int cb = 0; cb < 4; ++cb) {
            const size_t gi = xbase + (size_t)row*DD + cb*16 + lo;
            const float o  = T1[cb][r] * invZ;
            const float vo = (T2[cb][r]*IRD2 + sv*T4[cb][r] + T5[cb][r]) * invZ2
                           - 2.f * T3[cb][r] * IRD2 * invZ2 * invZ;
            om[gi] = x[gi] + o;
            ov[gi] = vx[gi] + vo;
        }
    }
#undef IK
#undef IV
#undef STAGE
}

extern "C" void kernel_launch(void* const* d_in, const int* in_sizes, int n_in,
                              void* d_out, int out_size, void* d_ws, size_t ws_size,
                              hipStream_t stream) {
    const float* x    = (const float*)d_in[0];
    const float* vx   = (const float*)d_in[1];
    const float* Wq   = (const float*)d_in[2];
    const float* vWq  = (const float*)d_in[3];
    const float* Wk   = (const float*)d_in[4];
    const float* vWk  = (const float*)d_in[5];
    const float* Wv   = (const float*)d_in[6];
    const float* vWv  = (const float*)d_in[7];

    const size_t NE = (size_t)MM * DD;

    unsigned short* u = (unsigned short*)d_ws;
    unsigned short* qm   = u + 0*NE;
    unsigned short* qv   = u + 1*NE;
    unsigned short* km   = u + 2*NE;
    unsigned short* kv   = u + 3*NE;
    unsigned short* vm   = u + 4*NE;
    unsigned short* vvv  = u + 5*NE;
    unsigned short* xbb  = u + 6*NE;   // after gemms: reused as vt
    unsigned short* vxbb = u + 7*NE;   // after gemms: unused
    unsigned short* xsbb = u + 8*NE;   // after gemms: reused as vvt
    unsigned short* wp   = u + 9*NE;   // 9 weight mats; after gemms: reused as kk

    float* om = (float*)d_out;
    float* ov = om + NE;

    prep_xw_kernel<<<7168, 256, 0, stream>>>(x, vx, Wq, vWq, Wk, vWk, Wv, vWv,
                                             xbb, vxbb, xsbb, wp);

    dim3 gg(8, 32, 6);
    gemm_proj_kernel<<<gg, 256, 0, stream>>>(xbb, vxbb, xsbb, wp,
                                             qm, km, vm, qv, kv, vvv);

    unsigned short* vt  = xbb;
    unsigned short* vvt = xsbb;
    unsigned short* kkb = wp;
    prep_vtkk_kernel<<<3072, 256, 0, stream>>>(vm, vvv, km, kv,
                                               vt, vvt, kkb);

    attn_mfma_kernel<<<1024, 256, 0, stream>>>(km, kv, kkb, vt, vvt,
                                               qm, qv, x, vx, om, ov);
}

// Round 15
// 197.889 us; speedup vs baseline: 1.2849x; 1.0843x over previous
//
#include <hip/hip_runtime.h>
#include <hip/hip_bf16.h>

#define BB 4
#define SS 1024
#define DD 1024
#define HH 16
#define DH 64
#define MM (BB*SS)   // 4096

typedef __attribute__((ext_vector_type(8))) short bf16x8;
typedef __attribute__((ext_vector_type(8))) unsigned short u16x8;
typedef __attribute__((ext_vector_type(4))) float f32x4;

__device__ __forceinline__ float b2f(unsigned short u) {
    union { unsigned int i; float f; } c; c.i = ((unsigned int)u) << 16; return c.f;
}
__device__ __forceinline__ unsigned short f2b(float f) {
    __hip_bfloat16 h = __float2bfloat16(f);
    return *reinterpret_cast<unsigned short*>(&h);
}
__device__ __forceinline__ unsigned int pack2(float a, float b) {
    unsigned int r;
    asm("v_cvt_pk_bf16_f32 %0, %1, %2" : "=v"(r) : "v"(a), "v"(b));
    return r;
}
__device__ __forceinline__ void gload16(const unsigned short* g, unsigned short* l) {
    __builtin_amdgcn_global_load_lds(
        (const __attribute__((address_space(1))) void*)g,
        (__attribute__((address_space(3))) void*)l,
        16, 0, 0);
}
#define MFMA16(a, b, c) __builtin_amdgcn_mfma_f32_16x16x32_bf16(a, b, c, 0, 0, 0)

// ---------------------------------------------------------------------------
// prep_xw: fused prep_x (blocks 0..4095) + prep_w (blocks 4096..7167).
// ---------------------------------------------------------------------------
__global__ __launch_bounds__(256) void prep_xw_kernel(
    const float* __restrict__ x, const float* __restrict__ vx,
    const float* __restrict__ W0, const float* __restrict__ vW0,
    const float* __restrict__ W1, const float* __restrict__ vW1,
    const float* __restrict__ W2, const float* __restrict__ vW2,
    unsigned short* __restrict__ xb, unsigned short* __restrict__ vxb,
    unsigned short* __restrict__ xsb, unsigned short* __restrict__ wp)
{
    const int gx = blockIdx.x;
    if (gx < 4096) {
        const size_t i = ((size_t)gx * 256 + threadIdx.x) * 4;
        float4 a = *(const float4*)(x + i);
        float4 b = *(const float4*)(vx + i);
        ushort4 oa = { f2b(a.x), f2b(a.y), f2b(a.z), f2b(a.w) };
        ushort4 ob = { f2b(b.x), f2b(b.y), f2b(b.z), f2b(b.w) };
        ushort4 os = { f2b(a.x*a.x), f2b(a.y*a.y), f2b(a.z*a.z), f2b(a.w*a.w) };
        *(ushort4*)(xb  + i) = oa;
        *(ushort4*)(vxb + i) = ob;
        *(ushort4*)(xsb + i) = os;
    } else {
        const int bxx = gx - 4096;
        const int z   = bxx >> 10;
        const int bx  = bxx & 1023;
        const float* W  = (z==0)? W0 : (z==1)? W1 : W2;
        const float* vW = (z==0)? vW0: (z==1)? vW1: vW2;
        const size_t NW = (size_t)DD*DD;
        unsigned short* wb = wp + (size_t)(3*z+0)*NW;
        unsigned short* wc = wp + (size_t)(3*z+1)*NW;
        unsigned short* wv = wp + (size_t)(3*z+2)*NW;
        const size_t i = ((size_t)bx * 256 + threadIdx.x) * 4;
        float4 a = *(const float4*)(W + i);
        float4 b = *(const float4*)(vW + i);
        ushort4 oa = { f2b(a.x), f2b(a.y), f2b(a.z), f2b(a.w) };
        ushort4 oc = { f2b(a.x*a.x + b.x), f2b(a.y*a.y + b.y),
                       f2b(a.z*a.z + b.z), f2b(a.w*a.w + b.w) };
        ushort4 ov = { f2b(b.x), f2b(b.y), f2b(b.z), f2b(b.w) };
        *(ushort4*)(wb + i) = oa;
        *(ushort4*)(wc + i) = oc;
        *(ushort4*)(wv + i) = ov;
    }
}

// ---------------------------------------------------------------------------
// Fused projection GEMM (one dispatch, z = 0..5) — R6 structure + T1 swizzle.
// ---------------------------------------------------------------------------
__global__ __launch_bounds__(256) void gemm_proj_kernel(
    const unsigned short* __restrict__ xb, const unsigned short* __restrict__ vxb,
    const unsigned short* __restrict__ xsb,
    const unsigned short* __restrict__ wp,
    unsigned short* __restrict__ qm, unsigned short* __restrict__ km,
    unsigned short* __restrict__ vm,
    unsigned short* __restrict__ qv, unsigned short* __restrict__ kv,
    unsigned short* __restrict__ vvv)
{
    __shared__ unsigned short sA[2][128*32];
    __shared__ unsigned short sB[2][128*32];

    const int z = blockIdx.z;
    const size_t NW = (size_t)DD*DD;
    const bool isVar = (z >= 3);
    const int p = isVar ? (z - 3) : z;
    const unsigned short* A0 = isVar ? vxb : xb;
    const unsigned short* A1 = isVar ? xsb : xb;
    const unsigned short* B0 = wp + (size_t)(3*p + (isVar ? 1 : 0)) * NW;
    const unsigned short* B1 = isVar ? (wp + (size_t)(3*p + 2) * NW) : B0;
    unsigned short* Out = (z==0)? qm : (z==1)? km : (z==2)? vm
                        : (z==3)? qv : (z==4)? kv : vvv;
    const int NT = isVar ? 64 : 32;

    const int orig = blockIdx.x + (blockIdx.y << 3);
    const int swz  = ((orig & 7) << 5) | (orig >> 3);
    const int bn = swz & 7;
    const int bm = swz >> 3;

    const int tid = threadIdx.x;
    const int w = tid >> 6;
    const int l = tid & 63;
    const int wr = w >> 1, wc = w & 1;

    const int r0 = tid >> 2;
    const int s0 = (((tid & 3) ^ ((r0 >> 1) & 3)) * 8);
    const size_t aoff0 = (size_t)(bm*128 + r0) * DD + s0;
    const size_t boff0 = (size_t)(bn*128 + r0) * DD + s0;
    const int ldsd0 = (w*64) * 8;
    const int ldsd1 = (256 + w*64) * 8;

#define STG(buf, t) do {                                                   \
        const unsigned short* As_ = ((t) < 32) ? A0 : A1;                  \
        const unsigned short* Bs_ = ((t) < 32) ? B0 : B1;                  \
        const int kc_ = ((t) & 31) * 32;                                   \
        gload16(As_ + aoff0 + kc_,                   &sA[buf][ldsd0]);     \
        gload16(As_ + aoff0 + (size_t)64*DD + kc_,   &sA[buf][ldsd1]);     \
        gload16(Bs_ + boff0 + kc_,                   &sB[buf][ldsd0]);     \
        gload16(Bs_ + boff0 + (size_t)64*DD + kc_,   &sB[buf][ldsd1]);     \
    } while (0)

    f32x4 acc[4][4];
    #pragma unroll
    for (int i = 0; i < 4; ++i)
        #pragma unroll
        for (int j = 0; j < 4; ++j)
            acc[i][j] = (f32x4){0.f,0.f,0.f,0.f};

    const int fr = l & 15;
    const int hi = l >> 4;

    STG(0, 0);
    __syncthreads();

    for (int t = 0; t < NT; ++t) {
        const int cb = t & 1;
        if (t + 1 < NT) STG(cb ^ 1, t + 1);

        bf16x8 bfr[4];
        #pragma unroll
        for (int j = 0; j < 4; ++j) {
            const int row = wc*64 + j*16 + fr;
            bfr[j] = *(const bf16x8*)&sB[cb][row*32 + ((hi ^ ((row >> 1) & 3)) * 8)];
        }
        #pragma unroll
        for (int i = 0; i < 4; ++i) {
            const int row = wr*64 + i*16 + fr;
            bf16x8 a0 = *(const bf16x8*)&sA[cb][row*32 + ((hi ^ ((row >> 1) & 3)) * 8)];
            #pragma unroll
            for (int j = 0; j < 4; ++j)
                acc[i][j] = MFMA16(a0, bfr[j], acc[i][j]);
        }
        __syncthreads();
    }
#undef STG

    const int orow = bm*128 + wr*64 + (hi << 2);
    const int ocol = bn*128 + wc*64 + fr;
    #pragma unroll
    for (int i = 0; i < 4; ++i)
        #pragma unroll
        for (int j = 0; j < 4; ++j)
            #pragma unroll
            for (int r = 0; r < 4; ++r)
                Out[(size_t)(orow + i*16 + r) * DD + ocol + j*16] = f2b(acc[i][j][r]);
}

// ---------------------------------------------------------------------------
// prep_vtkk: fused V-transpose (+w=vv+v^2) [blocks 0..1023] and
// kk = vk + k^2 elementwise [blocks 1024..3071].
// ---------------------------------------------------------------------------
__global__ __launch_bounds__(256) void prep_vtkk_kernel(
    const unsigned short* __restrict__ vm, const unsigned short* __restrict__ vvv,
    const unsigned short* __restrict__ kmp, const unsigned short* __restrict__ kvp,
    unsigned short* __restrict__ vt, unsigned short* __restrict__ wt,
    unsigned short* __restrict__ vvt, unsigned short* __restrict__ kkb)
{
    __shared__ unsigned short tv[64][68];
    __shared__ unsigned short tw[64][68];
    __shared__ unsigned short tvv[64][68];
    const int t = threadIdx.x;
    const int gx = blockIdx.x;

    if (gx >= 1024) {
        const size_t i = ((size_t)(gx - 1024) * 256 + t) * 8;
        u16x8 k8 = *(const u16x8*)(kmp + i);
        u16x8 v8 = *(const u16x8*)(kvp + i);
        u16x8 o8;
        #pragma unroll
        for (int e = 0; e < 8; ++e) {
            float kf = b2f(k8[e]);
            o8[e] = f2b(b2f(v8[e]) + kf*kf);
        }
        *(u16x8*)(kkb + i) = o8;
        return;
    }

    const int jt = gx & 15, h = (gx >> 4) & 15, b = gx >> 8;
    const size_t ibase = (size_t)b*SS*DD + (size_t)h*DH;
    {
        const int j = t & 63, cg = t >> 6;
        const size_t ga = ibase + (size_t)(jt*64 + j)*DD + cg*16;
        #pragma unroll
        for (int hh = 0; hh < 2; ++hh) {
            u16x8 v8  = *(const u16x8*)(vm  + ga + hh*8);
            u16x8 vv8 = *(const u16x8*)(vvv + ga + hh*8);
            u16x8 w8;
            #pragma unroll
            for (int e = 0; e < 8; ++e) {
                float vf = b2f(v8[e]);
                w8[e] = f2b(b2f(vv8[e]) + vf*vf);
            }
            *(u16x8*)&tv[j][cg*16 + hh*8]  = v8;
            *(u16x8*)&tvv[j][cg*16 + hh*8] = vv8;
            *(u16x8*)&tw[j][cg*16 + hh*8]  = w8;
        }
    }
    __syncthreads();
    {
        const int d  = t >> 2;
        const int pc = t & 3;
        const int lc = pc ^ ((d >> 1) & 3);
        #pragma unroll
        for (int st = 0; st < 2; ++st) {
            u16x8 o0, o1, o2;
            #pragma unroll
            for (int e = 0; e < 8; ++e) {
                const int jl = st*32 + (e >> 2)*16 + lc*4 + (e & 3);
                o0[e] = tv[jl][d];
                o1[e] = tw[jl][d];
                o2[e] = tvv[jl][d];
            }
            const size_t ob = (size_t)((b*HH + h)*DH + d)*SS + jt*64 + st*32 + pc*8;
            *(u16x8*)(vt  + ob) = o0;
            *(u16x8*)(wt  + ob) = o1;
            *(u16x8*)(vvt + ob) = o2;
        }
    }
}

// ---------------------------------------------------------------------------
// MFMA attention VMP + residual — EXACT R8 winner (102 us).
// 4 waves, QBLK=64, grid 1024, 2 blocks/CU; swapped QK -> P in regs;
// double-buffered K/V gload_lds; exp2-KE fold; deferred 1/D; setprio PV;
// v_cvt_pk_bf16_f32 P packing.
// ---------------------------------------------------------------------------
union PW { unsigned int u[4]; bf16x8 v; };

__global__ __launch_bounds__(256, 3) void attn_mfma_kernel(
    const unsigned short* __restrict__ kmg, const unsigned short* __restrict__ kvg,
    const unsigned short* __restrict__ kkg,
    const unsigned short* __restrict__ vtg, const unsigned short* __restrict__ wtg,
    const unsigned short* __restrict__ vvtg,
    const unsigned short* __restrict__ qmg, const unsigned short* __restrict__ qvg,
    const float* __restrict__ x, const float* __restrict__ vx,
    float* __restrict__ om, float* __restrict__ ov)
{
    __shared__ unsigned short Ks[2][3][32*64];
    __shared__ unsigned short Vs[2][3][64*32];

    const int tid = threadIdx.x;
    const int w = tid >> 6, l = tid & 63;
    const int lo = l & 15, hi = l >> 4;

    const int fb = blockIdx.x;
    const int g  = ((fb >> 7) << 3) | (fb & 7);   // 0..63 = b*16+h
    const int qt = (fb >> 3) & 15;
    const int h  = g & 15;
    const int b  = g >> 4;

    const size_t xbase = (size_t)b*SS*DD + (size_t)h*DH;
    const size_t vbase = (size_t)(b*HH + h)*DH*SS;

    bf16x8 qA[2], vqA[2], qsA[2];
    {
        const int qrow = qt*64 + w*16 + lo;
        #pragma unroll
        for (int ks = 0; ks < 2; ++ks) {
            const size_t ga = xbase + (size_t)qrow*DD + ks*32 + hi*8;
            qA[ks]  = *(const bf16x8*)(qmg + ga);
            vqA[ks] = *(const bf16x8*)(qvg + ga);
            #pragma unroll
            for (int e = 0; e < 8; ++e) {
                float f = b2f((unsigned short)qA[ks][e]);
                qsA[ks][e] = (short)f2b(f*f);
            }
        }
    }
    bf16x8 onesB;
    #pragma unroll
    for (int e = 0; e < 8; ++e) onesB[e] = (short)0x3F80;

    f32x4 T1[4], T2[4], T3[4], T4[4], T5[4];
    f32x4 zac = {0.f,0.f,0.f,0.f}, e2vac = {0.f,0.f,0.f,0.f};
    #pragma unroll
    for (int cb = 0; cb < 4; ++cb) {
        T1[cb] = (f32x4){0.f,0.f,0.f,0.f};
        T2[cb] = (f32x4){0.f,0.f,0.f,0.f};
        T3[cb] = (f32x4){0.f,0.f,0.f,0.f};
        T4[cb] = (f32x4){0.f,0.f,0.f,0.f};
        T5[cb] = (f32x4){0.f,0.f,0.f,0.f};
    }

    const size_t koff = (size_t)(l >> 3)*DD + (size_t)(((l & 7) ^ ((l >> 3) & 7)) * 8);
    const size_t voff = (size_t)(l >> 2)*SS + (size_t)((l & 3) * 8);

    const float KE = 0.03125f * 1.44269504f;   // 1/sqrt(D) * log2(e)

#define IK(bu, m, p, G) gload16(G + xbase + (j0 + (size_t)(p)*8)*DD + koff, &Ks[bu][m][(p)*512])
#define IV(bu, m, p, G) gload16(G + vbase + (size_t)((p)*16)*SS + j0 + voff, &Vs[bu][m][(p)*512])
#define STAGE(tt, bu) do {                                                     \
        const size_t j0 = (size_t)(tt) * 32;                                   \
        if (w == 0)      { IK(bu,0,0,kmg); IK(bu,0,1,kmg); IK(bu,0,2,kmg);     \
                           IK(bu,0,3,kmg); IK(bu,1,0,kvg); IK(bu,1,1,kvg); }   \
        else if (w == 1) { IK(bu,1,2,kvg); IK(bu,1,3,kvg); IK(bu,2,0,kkg);     \
                           IK(bu,2,1,kkg); IK(bu,2,2,kkg); IK(bu,2,3,kkg); }   \
        else if (w == 2) { IV(bu,0,0,vtg); IV(bu,0,1,vtg); IV(bu,0,2,vtg);     \
                           IV(bu,0,3,vtg); IV(bu,1,0,wtg); IV(bu,1,1,wtg); }   \
        else             { IV(bu,1,2,wtg); IV(bu,1,3,wtg); IV(bu,2,0,vvtg);    \
                           IV(bu,2,1,vvtg); IV(bu,2,2,vvtg); IV(bu,2,3,vvtg); }\
    } while (0)

    STAGE(0, 0);
    __syncthreads();

    int cur = 0;
    for (int t = 0; t < SS/32; ++t) {
        if (t + 1 < SS/32) STAGE(t + 1, cur ^ 1);

        PW pe, pe2, pev, pe3;
        #pragma unroll
        for (int jb = 0; jb < 2; ++jb) {
            f32x4 aa = {0.f,0.f,0.f,0.f}, vva = {0.f,0.f,0.f,0.f};
            const int jrow = jb*16 + lo;
            #pragma unroll
            for (int ks = 0; ks < 2; ++ks) {
                const int co = jrow*64 + (((ks*4 + hi) ^ (lo & 7)) * 8);
                bf16x8 kB  = *(const bf16x8*)&Ks[cur][0][co];
                bf16x8 vkB = *(const bf16x8*)&Ks[cur][1][co];
                bf16x8 kkB = *(const bf16x8*)&Ks[cur][2][co];
                aa  = MFMA16(kB,  qA[ks],  aa);
                vva = MFMA16(kkB, vqA[ks], vva);
                vva = MFMA16(vkB, qsA[ks], vva);
            }
            #pragma unroll
            for (int rp = 0; rp < 2; ++rp) {
                float e0 = exp2f(aa[rp*2]   * KE);
                float e1 = exp2f(aa[rp*2+1] * KE);
                float va0 = vva[rp*2], va1 = vva[rp*2+1];   // unscaled (x1024)
                float s0 = e0*e0,  s1 = e1*e1;
                float v0 = s0*va0, v1 = s1*va1;
                float t0 = v0*e0,  t1 = v1*e1;
                pe.u [jb*2+rp] = pack2(e0, e1);
                pe2.u[jb*2+rp] = pack2(s0, s1);
                pev.u[jb*2+rp] = pack2(v0, v1);
                pe3.u[jb*2+rp] = pack2(t0, t1);
            }
        }

        __builtin_amdgcn_s_setprio(1);
        zac   = MFMA16(pe.v,  onesB, zac);
        e2vac = MFMA16(pev.v, onesB, e2vac);
        #pragma unroll
        for (int cb = 0; cb < 4; ++cb) {
            const int vo = (cb*16 + lo)*32 + ((hi ^ ((lo >> 1) & 3)) * 8);
            bf16x8 vB  = *(const bf16x8*)&Vs[cur][0][vo];
            bf16x8 wB  = *(const bf16x8*)&Vs[cur][1][vo];
            bf16x8 vvB = *(const bf16x8*)&Vs[cur][2][vo];
            T1[cb] = MFMA16(pe.v,  vB,  T1[cb]);
            T2[cb] = MFMA16(pev.v, wB,  T2[cb]);
            T3[cb] = MFMA16(pe3.v, wB,  T3[cb]);
            T4[cb] = MFMA16(pe2.v, wB,  T4[cb]);
            T5[cb] = MFMA16(pe2.v, vvB, T5[cb]);
        }
        __builtin_amdgcn_s_setprio(0);

        __syncthreads();
        cur ^= 1;
    }

    const float IRD2 = 0.0009765625f;
    #pragma unroll
    for (int r = 0; r < 4; ++r) {
        const float Z     = zac[r];
        const float invZ  = 1.f / Z;
        const float invZ2 = invZ * invZ;
        const float sv    = e2vac[r] * IRD2 * invZ2;
        const int row = qt*64 + w*16 + hi*4 + r;
        #pragma unroll
        for (int cb = 0; cb < 4; ++cb) {
            const size_t gi = xbase + (size_t)row*DD + cb*16 + lo;
            const float o  = T1[cb][r] * invZ;
            const float vo = (T2[cb][r]*IRD2 + sv*T4[cb][r] + T5[cb][r]) * invZ2
                           - 2.f * T3[cb][r] * IRD2 * invZ2 * invZ;
            om[gi] = x[gi] + o;
            ov[gi] = vx[gi] + vo;
        }
    }
#undef IK
#undef IV
#undef STAGE
}

extern "C" void kernel_launch(void* const* d_in, const int* in_sizes, int n_in,
                              void* d_out, int out_size, void* d_ws, size_t ws_size,
                              hipStream_t stream) {
    const float* x    = (const float*)d_in[0];
    const float* vx   = (const float*)d_in[1];
    const float* Wq   = (const float*)d_in[2];
    const float* vWq  = (const float*)d_in[3];
    const float* Wk   = (const float*)d_in[4];
    const float* vWk  = (const float*)d_in[5];
    const float* Wv   = (const float*)d_in[6];
    const float* vWv  = (const float*)d_in[7];

    const size_t NE = (size_t)MM * DD;

    unsigned short* u = (unsigned short*)d_ws;
    unsigned short* qm   = u + 0*NE;
    unsigned short* qv   = u + 1*NE;
    unsigned short* km   = u + 2*NE;
    unsigned short* kv   = u + 3*NE;
    unsigned short* vm   = u + 4*NE;
    unsigned short* vvv  = u + 5*NE;
    unsigned short* xbb  = u + 6*NE;   // after gemms: reused as vt
    unsigned short* vxbb = u + 7*NE;   // after gemms: reused as wt
    unsigned short* xsbb = u + 8*NE;   // after gemms: reused as vvt
    unsigned short* wp   = u + 9*NE;   // 9 weight mats; after gemms: reused as kk

    float* om = (float*)d_out;
    float* ov = om + NE;

    prep_xw_kernel<<<7168, 256, 0, stream>>>(x, vx, Wq, vWq, Wk, vWk, Wv, vWv,
                                             xbb, vxbb, xsbb, wp);

    dim3 gg(8, 32, 6);
    gemm_proj_kernel<<<gg, 256, 0, stream>>>(xbb, vxbb, xsbb, wp,
                                             qm, km, vm, qv, kv, vvv);

    unsigned short* vt  = xbb;
    unsigned short* wt  = vxbb;
    unsigned short* vvt = xsbb;
    unsigned short* kkb = wp;
    prep_vtkk_kernel<<<3072, 256, 0, stream>>>(vm, vvv, km, kv,
                                               vt, wt, vvt, kkb);

    attn_mfma_kernel<<<1024, 256, 0, stream>>>(km, kv, kkb, vt, wt, vvt,
                                               qm, qv, x, vx, om, ov);
}